// Round 7
// baseline (42.757 us; speedup 1.0000x reference)
//
#include <hip/hip_runtime.h>

#define BATCH 32
#define SS 1024
#define NSTEPS 972
#define LSTR 20                     // floats per lane row: 16 data + 4 pad = 80B (16B-aligned, 8-way bank spread)

#define UNVIS   0x7F000000u         // huge finite float sentinels: UNVIS < CLOSED < OBST, all > any real f
#define CLOSEDB 0x7F000001u
#define OBSTB   0x7F000002u

typedef unsigned long long ull;

template <int CTRL>
__device__ __forceinline__ int dpp32(int v) {
    return __builtin_amdgcn_update_dpp(v, v, CTRL, 0xF, 0xF, false);
}

// 64-lane f32 min, result (bit-exact copy of some input) broadcast from lane 63.
__device__ __forceinline__ float wave_min_f32_bcast(float v) {
    float t;
    t = __int_as_float(dpp32<0xB1 >(__float_as_int(v))); v = fminf(v, t);  // quad xor1
    t = __int_as_float(dpp32<0x4E >(__float_as_int(v))); v = fminf(v, t);  // quad xor2
    t = __int_as_float(dpp32<0x141>(__float_as_int(v))); v = fminf(v, t);  // row_half_mirror
    t = __int_as_float(dpp32<0x140>(__float_as_int(v))); v = fminf(v, t);  // row_mirror
    t = __int_as_float(dpp32<0x142>(__float_as_int(v))); v = fminf(v, t);  // row_bcast15
    t = __int_as_float(dpp32<0x143>(__float_as_int(v))); v = fminf(v, t);  // row_bcast31
    return __int_as_float(__builtin_amdgcn_readlane(__float_as_int(v), 63));
}

__device__ __forceinline__ unsigned umin2(unsigned a, unsigned b) { return a < b ? a : b; }
__device__ __forceinline__ unsigned slotc(float v, unsigned lm, unsigned i) {
    return (__float_as_uint(v) == lm) ? i : 63u;   // lane-local slot candidate
}

__global__ __launch_bounds__(64)
void astar_kernel(const float* __restrict__ start_maps,
                  const float* __restrict__ goal_maps,
                  const float* __restrict__ obst_maps,
                  float* __restrict__ out)
{
    const int b = blockIdx.x;
    const int lane = threadIdx.x;

    __shared__ __align__(16) float fop[64 * LSTR];   // padded: cell c at (c>>4)*LSTR + (c&15)
    __shared__ __align__(16) float g_s[SS];
    __shared__ __align__(16) float fh_s[SS];         // 0.501f * h
    __shared__ unsigned short par_s[SS];
    __shared__ int sh_start, sh_goal;

    const float* st = start_maps + b * SS;
    const float* gl = goal_maps + b * SS;
    const float* ob = obst_maps + b * SS;

    for (int i = 0; i < 16; ++i) {
        int c = i * 64 + lane;
        if (st[c] > 0.5f) sh_start = c;
        if (gl[c] > 0.5f) sh_goal = c;
    }
    __syncthreads();
    const int start_idx = sh_start;
    const int goal_idx = sh_goal;
    const float gi = (float)(goal_idx >> 5);
    const float gj = (float)(goal_idx & 31);
    const float SQRT2F = 1.41421356237309515f;   // fl32(sqrt(2))
    const float WH = 0.501f;

    for (int i = 0; i < 16; ++i) {
        int c = i * 64 + lane;
        float dx = fabsf((float)(c >> 5) - gi);
        float dy = fabsf((float)(c & 31) - gj);
        float h = __fadd_rn(__fmul_rn(fminf(dx, dy), SQRT2F), fabsf(dx - dy));
        fh_s[c] = __fmul_rn(WH, h);
        g_s[c] = 0.0f;
        par_s[c] = (unsigned short)goal_idx;
        fop[(c >> 4) * LSTR + (c & 15)] = __uint_as_float(ob[c] > 0.5f ? UNVIS : OBSTB);
    }
    __syncthreads();
    if (lane == 0)
        fop[(start_idx >> 4) * LSTR + (start_idx & 15)] = fh_s[start_idx];  // f = fl(0.5*0 + fh) = fh
    __syncthreads();

    const float* frow = &fop[lane * LSTR];
    float4 r0 = *(const float4*)(frow + 0);
    float4 r1 = *(const float4*)(frow + 4);
    float4 r2 = *(const float4*)(frow + 8);
    float4 r3 = *(const float4*)(frow + 12);
    bool solved = false;

    #pragma unroll 1
    for (int step = 0; step < NSTEPS; ++step) {
        // ---- local value min over this lane's 16 cells (v_min3-friendly tree) ----
        float a0 = fminf(fminf(r0.x, r0.y), fminf(r0.z, r0.w));
        float a1 = fminf(fminf(r1.x, r1.y), fminf(r1.z, r1.w));
        float a2 = fminf(fminf(r2.x, r2.y), fminf(r2.z, r2.w));
        float a3 = fminf(fminf(r3.x, r3.y), fminf(r3.z, r3.w));
        float lmin = fminf(fminf(a0, a1), fminf(a2, a3));
        const unsigned lm = __float_as_uint(lmin);

        // ---- local slot (lowest i with bits==lm); independent of the DPP chain -> overlaps ----
        unsigned s0 = umin2(umin2(slotc(r0.x, lm, 0),  slotc(r0.y, lm, 1)),
                            umin2(slotc(r0.z, lm, 2),  slotc(r0.w, lm, 3)));
        unsigned s1 = umin2(umin2(slotc(r1.x, lm, 4),  slotc(r1.y, lm, 5)),
                            umin2(slotc(r1.z, lm, 6),  slotc(r1.w, lm, 7)));
        unsigned s2 = umin2(umin2(slotc(r2.x, lm, 8),  slotc(r2.y, lm, 9)),
                            umin2(slotc(r2.z, lm, 10), slotc(r2.w, lm, 11)));
        unsigned s3 = umin2(umin2(slotc(r3.x, lm, 12), slotc(r3.y, lm, 13)),
                            umin2(slotc(r3.z, lm, 14), slotc(r3.w, lm, 15)));
        unsigned slot = umin2(umin2(s0, s1), umin2(s2, s3));

        // ---- wave min + owner (lowest lane among ties == lowest cell block) ----
        const float gmin = wave_min_f32_bcast(lmin);
        const ull bal = __ballot(lm == __float_as_uint(gmin));
        const int owner = (int)__builtin_ctzll(bal);
        const int sel = owner * 16 + __builtin_amdgcn_readlane((int)slot, owner);
        solved = (sel == goal_idx);
        const int si = sel >> 5, sj = sel & 31;

        // close sel (distinct address from all neighbor reads below)
        if (lane == 0)
            fop[(sel >> 4) * LSTR + (sel & 15)] = __uint_as_float(CLOSEDB);
        asm volatile("" ::: "memory");

        // gsel: uniform LDS broadcast read, batched with the relax reads -> one lgkm wait
        const float gsel = g_s[sel];

        // ---- 8-neighbor relax ----
        if (lane < 8) {
            int k = lane < 4 ? lane : lane + 1;   // skip center
            int di = k / 3 - 1;
            int dj = k - (k / 3) * 3 - 1;
            int ni = si + di, nj = sj + dj;
            if ((unsigned)ni < 32u && (unsigned)nj < 32u) {
                int nb = ni * 32 + nj;
                int fa = (nb >> 4) * LSTR + (nb & 15);
                unsigned fbv = __float_as_uint(fop[fa]);
                float gnb = g_s[nb];
                float fh = fh_s[nb];
                float w = (di != 0 && dj != 0) ? SQRT2F : 1.0f;
                float g2 = __fadd_rn(gsel, w);
                // UNVIS -> open; CLOSED/OBST (> UNVIS) -> skip; open (< UNVIS) -> strict g improvement
                bool rel = (fbv == UNVIS) || (fbv < UNVIS && gnb > g2);
                if (rel) {
                    fop[fa] = __fadd_rn(__fmul_rn(0.5f, g2), fh);
                    g_s[nb] = g2;
                    par_s[nb] = (unsigned short)sel;
                }
            }
        }
        asm volatile("" ::: "memory");
        // next-step scan loads: issued AFTER relax writes (in-order DS -> they see the
        // close + all relaxes); latency partially hidden by loop-back + value tree wait
        r0 = *(const float4*)(frow + 0);
        r1 = *(const float4*)(frow + 4);
        r2 = *(const float4*)(frow + 8);
        r3 = *(const float4*)(frow + 12);
        asm volatile("" ::: "memory");

        if (solved) break;   // exact: state provably constant after goal selection
    }

    float* out_hist = out + b * SS;
    float* out_path = out + BATCH * SS + b * SS;
    float* out_g    = out + 2 * BATCH * SS + b * SS;
    for (int i = 0; i < 16; ++i) {
        int c = i * 64 + lane;
        unsigned fbv = __float_as_uint(fop[(c >> 4) * LSTR + (c & 15)]);
        out_hist[c] = (fbv == CLOSEDB) ? 1.0f : 0.0f;
        out_g[c]    = g_s[c];
        out_path[c] = (c == goal_idx) ? 1.0f : 0.0f;
    }
    __syncthreads();   // drain stores before backtrack overwrites
    if (lane == 0) {
        int loc = par_s[goal_idx];
        for (int it = 0; it < NSTEPS; ++it) {
            out_path[loc] = 1.0f;
            if (loc == goal_idx) break;   // parent chain strictly decreasing in expansion time
            loc = par_s[loc];
        }
    }
}

extern "C" void kernel_launch(void* const* d_in, const int* in_sizes, int n_in,
                              void* d_out, int out_size, void* d_ws, size_t ws_size,
                              hipStream_t stream)
{
    // d_in: [0]=cost_maps (unused in 'default' mode), [1]=start, [2]=goal, [3]=obstacles
    const float* start_maps = (const float*)d_in[1];
    const float* goal_maps  = (const float*)d_in[2];
    const float* obst_maps  = (const float*)d_in[3];
    float* out = (float*)d_out;
    hipLaunchKernelGGL(astar_kernel, dim3(BATCH), dim3(64), 0, stream,
                       start_maps, goal_maps, obst_maps, out);
}

// Round 8
// 42.750 us; speedup vs baseline: 1.0002x; 1.0002x over previous
//
#include <hip/hip_runtime.h>

#define BATCH 32
#define SS 1024
#define NSTEPS 972
#define LSTR 20                     // floats per lane row: 16 data + 4 pad = 80B (16B-aligned, 8-way bank spread)

#define UNVIS   0x7F000000u         // huge finite float sentinels: UNVIS < CLOSED < OBST, all > any real f
#define CLOSEDB 0x7F000001u
#define OBSTB   0x7F000002u

typedef unsigned long long ull;

template <int CTRL>
__device__ __forceinline__ int dpp32(int v) {
    return __builtin_amdgcn_update_dpp(v, v, CTRL, 0xF, 0xF, false);
}

// 64-lane f32 min, result (bit-exact copy of some input) broadcast from lane 63.
__device__ __forceinline__ float wave_min_f32_bcast(float v) {
    float t;
    t = __int_as_float(dpp32<0xB1 >(__float_as_int(v))); v = fminf(v, t);  // quad xor1
    t = __int_as_float(dpp32<0x4E >(__float_as_int(v))); v = fminf(v, t);  // quad xor2
    t = __int_as_float(dpp32<0x141>(__float_as_int(v))); v = fminf(v, t);  // row_half_mirror
    t = __int_as_float(dpp32<0x140>(__float_as_int(v))); v = fminf(v, t);  // row_mirror
    t = __int_as_float(dpp32<0x142>(__float_as_int(v))); v = fminf(v, t);  // row_bcast15
    t = __int_as_float(dpp32<0x143>(__float_as_int(v))); v = fminf(v, t);  // row_bcast31
    return __int_as_float(__builtin_amdgcn_readlane(__float_as_int(v), 63));
}

__device__ __forceinline__ unsigned umin2(unsigned a, unsigned b) { return a < b ? a : b; }
__device__ __forceinline__ unsigned slotc(float v, unsigned lm, unsigned i) {
    return (__float_as_uint(v) == lm) ? i : 63u;   // lane-local slot candidate
}

__global__ __launch_bounds__(64)
void astar_kernel(const float* __restrict__ start_maps,
                  const float* __restrict__ goal_maps,
                  const float* __restrict__ obst_maps,
                  float* __restrict__ out)
{
    const int b = blockIdx.x;
    const int lane = threadIdx.x;

    __shared__ __align__(16) float fop[64 * LSTR];   // padded: cell c at (c>>4)*LSTR + (c&15)
    __shared__ __align__(16) float g_s[SS];
    __shared__ __align__(16) float fh_s[SS];         // 0.501f * h
    __shared__ unsigned short par_s[SS];
    __shared__ int sh_start, sh_goal;

    const float* st = start_maps + b * SS;
    const float* gl = goal_maps + b * SS;
    const float* ob = obst_maps + b * SS;

    for (int i = 0; i < 16; ++i) {
        int c = i * 64 + lane;
        if (st[c] > 0.5f) sh_start = c;
        if (gl[c] > 0.5f) sh_goal = c;
    }
    __syncthreads();
    const int start_idx = sh_start;
    const int goal_idx = sh_goal;
    const float gi = (float)(goal_idx >> 5);
    const float gj = (float)(goal_idx & 31);
    const float SQRT2F = 1.41421356237309515f;   // fl32(sqrt(2))
    const float WH = 0.501f;

    for (int i = 0; i < 16; ++i) {
        int c = i * 64 + lane;
        float dx = fabsf((float)(c >> 5) - gi);
        float dy = fabsf((float)(c & 31) - gj);
        float h = __fadd_rn(__fmul_rn(fminf(dx, dy), SQRT2F), fabsf(dx - dy));
        fh_s[c] = __fmul_rn(WH, h);
        g_s[c] = 0.0f;
        par_s[c] = (unsigned short)goal_idx;
        fop[(c >> 4) * LSTR + (c & 15)] = __uint_as_float(ob[c] > 0.5f ? UNVIS : OBSTB);
    }
    __syncthreads();
    if (lane == 0)
        fop[(start_idx >> 4) * LSTR + (start_idx & 15)] = fh_s[start_idx];  // f = fl(0.5*0 + fh) = fh
    __syncthreads();

    const float* frow = &fop[lane * LSTR];
    float4 r0 = *(const float4*)(frow + 0);
    float4 r1 = *(const float4*)(frow + 4);
    float4 r2 = *(const float4*)(frow + 8);
    float4 r3 = *(const float4*)(frow + 12);
    bool solved = false;

    #pragma unroll 1
    for (int step = 0; step < NSTEPS; ++step) {
        // ---- local value min over this lane's 16 cells (v_min3-friendly tree) ----
        float a0 = fminf(fminf(r0.x, r0.y), fminf(r0.z, r0.w));
        float a1 = fminf(fminf(r1.x, r1.y), fminf(r1.z, r1.w));
        float a2 = fminf(fminf(r2.x, r2.y), fminf(r2.z, r2.w));
        float a3 = fminf(fminf(r3.x, r3.y), fminf(r3.z, r3.w));
        float lmin = fminf(fminf(a0, a1), fminf(a2, a3));
        const unsigned lm = __float_as_uint(lmin);

        // ---- local slot (lowest i with bits==lm); independent of the DPP chain -> overlaps ----
        unsigned s0 = umin2(umin2(slotc(r0.x, lm, 0),  slotc(r0.y, lm, 1)),
                            umin2(slotc(r0.z, lm, 2),  slotc(r0.w, lm, 3)));
        unsigned s1 = umin2(umin2(slotc(r1.x, lm, 4),  slotc(r1.y, lm, 5)),
                            umin2(slotc(r1.z, lm, 6),  slotc(r1.w, lm, 7)));
        unsigned s2 = umin2(umin2(slotc(r2.x, lm, 8),  slotc(r2.y, lm, 9)),
                            umin2(slotc(r2.z, lm, 10), slotc(r2.w, lm, 11)));
        unsigned s3 = umin2(umin2(slotc(r3.x, lm, 12), slotc(r3.y, lm, 13)),
                            umin2(slotc(r3.z, lm, 14), slotc(r3.w, lm, 15)));
        unsigned slot = umin2(umin2(s0, s1), umin2(s2, s3));

        // ---- wave min + owner (lowest lane among ties == lowest cell block) ----
        const float gmin = wave_min_f32_bcast(lmin);
        const ull bal = __ballot(lm == __float_as_uint(gmin));
        const int owner = (int)__builtin_ctzll(bal);
        const int sel = owner * 16 + __builtin_amdgcn_readlane((int)slot, owner);
        solved = (sel == goal_idx);
        const int si = sel >> 5, sj = sel & 31;

        // close sel (distinct address from all neighbor reads below)
        if (lane == 0)
            fop[(sel >> 4) * LSTR + (sel & 15)] = __uint_as_float(CLOSEDB);
        asm volatile("" ::: "memory");

        // gsel: uniform LDS broadcast read, batched with the relax reads -> one lgkm wait
        const float gsel = g_s[sel];

        // ---- 8-neighbor relax ----
        if (lane < 8) {
            int k = lane < 4 ? lane : lane + 1;   // skip center
            int di = k / 3 - 1;
            int dj = k - (k / 3) * 3 - 1;
            int ni = si + di, nj = sj + dj;
            if ((unsigned)ni < 32u && (unsigned)nj < 32u) {
                int nb = ni * 32 + nj;
                int fa = (nb >> 4) * LSTR + (nb & 15);
                unsigned fbv = __float_as_uint(fop[fa]);
                float gnb = g_s[nb];
                float fh = fh_s[nb];
                float w = (di != 0 && dj != 0) ? SQRT2F : 1.0f;
                float g2 = __fadd_rn(gsel, w);
                // UNVIS -> open; CLOSED/OBST (> UNVIS) -> skip; open (< UNVIS) -> strict g improvement
                bool rel = (fbv == UNVIS) || (fbv < UNVIS && gnb > g2);
                if (rel) {
                    fop[fa] = __fadd_rn(__fmul_rn(0.5f, g2), fh);
                    g_s[nb] = g2;
                    par_s[nb] = (unsigned short)sel;
                }
            }
        }
        asm volatile("" ::: "memory");
        // next-step scan loads: issued AFTER relax writes (in-order DS -> they see the
        // close + all relaxes); latency partially hidden by loop-back + value tree wait
        r0 = *(const float4*)(frow + 0);
        r1 = *(const float4*)(frow + 4);
        r2 = *(const float4*)(frow + 8);
        r3 = *(const float4*)(frow + 12);
        asm volatile("" ::: "memory");

        if (solved) break;   // exact: state provably constant after goal selection
    }

    float* out_hist = out + b * SS;
    float* out_path = out + BATCH * SS + b * SS;
    float* out_g    = out + 2 * BATCH * SS + b * SS;
    for (int i = 0; i < 16; ++i) {
        int c = i * 64 + lane;
        unsigned fbv = __float_as_uint(fop[(c >> 4) * LSTR + (c & 15)]);
        out_hist[c] = (fbv == CLOSEDB) ? 1.0f : 0.0f;
        out_g[c]    = g_s[c];
        out_path[c] = (c == goal_idx) ? 1.0f : 0.0f;
    }
    __syncthreads();   // drain stores before backtrack overwrites
    if (lane == 0) {
        int loc = par_s[goal_idx];
        for (int it = 0; it < NSTEPS; ++it) {
            out_path[loc] = 1.0f;
            if (loc == goal_idx) break;   // parent chain strictly decreasing in expansion time
            loc = par_s[loc];
        }
    }
}

extern "C" void kernel_launch(void* const* d_in, const int* in_sizes, int n_in,
                              void* d_out, int out_size, void* d_ws, size_t ws_size,
                              hipStream_t stream)
{
    // d_in: [0]=cost_maps (unused in 'default' mode), [1]=start, [2]=goal, [3]=obstacles
    const float* start_maps = (const float*)d_in[1];
    const float* goal_maps  = (const float*)d_in[2];
    const float* obst_maps  = (const float*)d_in[3];
    float* out = (float*)d_out;
    hipLaunchKernelGGL(astar_kernel, dim3(BATCH), dim3(64), 0, stream,
                       start_maps, goal_maps, obst_maps, out);
}